// Round 3
// baseline (2628.424 us; speedup 1.0000x reference)
//
#include <hip/hip_runtime.h>
#include <math.h>

typedef unsigned long long u64;
typedef unsigned int u32;

#define HH 160
#define WW 160
#define CC 256
#define PH 162
#define PWD 168
#define NPX 25600
#define NA 9
#define NSC 230400
#define K_SEL 6000
#define SEL_PAD 6016
#define MROW 96
#define IMS 2560.0f
#define DWH 4.135166556742356f

struct SelState { u64 prefix; u32 r; u32 cnt; };

// ---- ws layout (bytes). Small buffers overlap pf (pf dead after conv). ----
#define OFF_BOXES   0u               // float4[230400] -> 3,686,400
#define OFF_SCORES  3686400u         // float [230400]
#define OFF_KEYS    4608000u         // u64   [230400]
#define OFF_HIST    6451200u         // u32   [65536]
#define OFF_STATE   6713344u
#define OFF_SELK    6713600u         // u64[6016]
#define OFF_SX1     6761728u
#define OFF_SY1     6785792u
#define OFF_SX2     6809856u
#define OFF_SY2     6833920u
#define OFF_SSC     6857984u
#define OFF_ALIVE   6882048u
#define OFF_MASKT   11503104u        // u64[94*6016] -> ends 16,027,136
#define OFF_PF      0u               // float[256*162*168] -> 27,869,184 (dead after conv)
#define OFF_RPN     27869184u        // float[256*160*160] -> ends 54,083,584

__constant__ float c_bx1[9] = {-91.f,-181.f,-362.f,-64.f,-128.f,-256.f,-45.f,-91.f,-181.f};
__constant__ float c_by1[9] = {-45.f,-91.f,-181.f,-64.f,-128.f,-256.f,-91.f,-181.f,-362.f};
__constant__ float c_bx2[9] = { 91.f, 181.f, 362.f, 64.f, 128.f, 256.f, 45.f, 91.f, 181.f};
__constant__ float c_by2[9] = { 45.f,  91.f, 181.f, 64.f, 128.f, 256.f, 91.f, 181.f, 362.f};

__device__ inline u64 shfl64(u64 v, int src) {
  int lo = (int)(v & 0xFFFFFFFFull), hi = (int)(v >> 32);
  lo = __shfl(lo, src, 64); hi = __shfl(hi, src, 64);
  return ((u64)(u32)hi << 32) | (u32)lo;
}

// ---------------- 1. zero-pad feat -> pf[256][162][168] ----------------
__global__ __launch_bounds__(256) void pad_k(const float* __restrict__ feat, float* __restrict__ pf) {
  int idx = blockIdx.x * 256 + threadIdx.x;           // 256*162*168 = 6,967,296
  int px = idx % PWD;
  int rest = idx / PWD;
  int py = rest % PH;
  int c  = rest / PH;
  float v = 0.f;
  if (py >= 1 && py <= 160 && px >= 1 && px <= 160)
    v = feat[(c * HH + (py - 1)) * WW + (px - 1)];
  pf[idx] = v;
}

// ---------------- 2. conv3x3 + bias + relu (implicit GEMM, fp32) ----------------
// tile 64 oc x (4 rows x 32 cols); per thread 8 oc x 4 px; b reused across dx,
// a via broadcast ds_read_b128. ps stride 36 / wsm stride 68 keep 16B alignment.
__global__ __launch_bounds__(256) void conv_k(const float* __restrict__ pf,
                                              const float* __restrict__ w,
                                              const float* __restrict__ bias,
                                              float* __restrict__ outp) {
  int bx = blockIdx.x;            // 800 = 5 * 40 * 4
  int ct = bx % 5;
  int rt = (bx / 5) % 40;
  int ot = bx / 200;
  int x0 = ct * 32, y0 = rt * 4, oc0 = ot * 64;

  __shared__ float wsm[72][68];   // [k = icl*9+tap][oc]
  __shared__ float ps[8][6][36];  // [icl][row][col]

  int tid = threadIdx.x;
  int og = tid >> 5;              // 0..7 -> oc group of 8
  int pg = tid & 31;              // 0..31
  int row = pg >> 3;              // 0..3
  int col = (pg & 7) * 4;         // 0,4,...,28

  float acc[8][4];
#pragma unroll
  for (int i = 0; i < 8; i++)
#pragma unroll
    for (int j = 0; j < 4; j++) acc[i][j] = 0.f;

  for (int ic0 = 0; ic0 < CC; ic0 += 8) {
    __syncthreads();
    for (int idx = tid; idx < 4608; idx += 256) {
      int oc = idx / 72, j = idx % 72;
      wsm[j][oc] = w[(oc0 + oc) * 2304 + ic0 * 9 + j];
    }
    for (int idx = tid; idx < 1632; idx += 256) {
      int icl = idx / 204, rem = idx % 204;
      int r = rem / 34, cc2 = rem % 34;
      ps[icl][r][cc2] = pf[(ic0 + icl) * (PH * PWD) + (y0 + r) * PWD + (x0 + cc2)];
    }
    __syncthreads();
#pragma unroll
    for (int icl = 0; icl < 8; icl++) {
#pragma unroll
      for (int dy = 0; dy < 3; dy++) {
        float4 b03 = *(const float4*)&ps[icl][row + dy][col];
        float2 b45 = *(const float2*)&ps[icl][row + dy][col + 4];
        float bb[6] = {b03.x, b03.y, b03.z, b03.w, b45.x, b45.y};
#pragma unroll
        for (int dxx = 0; dxx < 3; dxx++) {
          int k = icl * 9 + dy * 3 + dxx;
          float4 a03 = *(const float4*)&wsm[k][og * 8];
          float4 a47 = *(const float4*)&wsm[k][og * 8 + 4];
          float av[8] = {a03.x, a03.y, a03.z, a03.w, a47.x, a47.y, a47.z, a47.w};
#pragma unroll
          for (int i = 0; i < 8; i++)
#pragma unroll
            for (int j = 0; j < 4; j++)
              acc[i][j] += av[i] * bb[dxx + j];
        }
      }
    }
  }
#pragma unroll
  for (int i = 0; i < 8; i++) {
    int oc = oc0 + og * 8 + i;
    float bv = bias[oc];
    float4 v;
    v.x = fmaxf(acc[i][0] + bv, 0.f);
    v.y = fmaxf(acc[i][1] + bv, 0.f);
    v.z = fmaxf(acc[i][2] + bv, 0.f);
    v.w = fmaxf(acc[i][3] + bv, 0.f);
    *(float4*)&outp[(size_t)oc * NPX + (y0 + row) * WW + x0 + col] = v;
  }
}

// ---------------- 3. heads + sigmoid + decode + clip + key ----------------
__global__ __launch_bounds__(256) void heads_k(const float* __restrict__ rpn,
                                               const float* __restrict__ cls_w,
                                               const float* __restrict__ cls_b,
                                               const float* __restrict__ bbox_w,
                                               const float* __restrict__ bbox_b,
                                               float4* __restrict__ boxes,
                                               float* __restrict__ scores,
                                               u64* __restrict__ keys) {
  __shared__ float sf[32][260];   // [pixel][channel], padded
  __shared__ float so[45][33];    // [output][pixel]
  int tid = threadIdx.x;
  int px0 = blockIdx.x * 32;
  for (int idx = tid; idx < 8192; idx += 256) {
    int c = idx >> 5, p = idx & 31;
    sf[p][c] = rpn[(size_t)c * NPX + px0 + p];
  }
  __syncthreads();
  int p = tid & 31, g = tid >> 5;
  for (int oi = 0; oi < 6; oi++) {
    int o = g + oi * 8;
    if (o >= 45) break;
    const float* wr = (o < 9) ? (cls_w + o * CC) : (bbox_w + (o - 9) * CC);
    float bsum = (o < 9) ? cls_b[o] : bbox_b[o - 9];
    float s = 0.f;
    for (int c = 0; c < CC; c += 4) {
      float4 f = *(const float4*)&sf[p][c];
      float4 wv = *(const float4*)&wr[c];
      s += f.x * wv.x; s += f.y * wv.y; s += f.z * wv.z; s += f.w * wv.w;
    }
    so[o][p] = s + bsum;
  }
  __syncthreads();
  for (int t = tid; t < 288; t += 256) {
    int a = t >> 5, pp = t & 31;
    int px = px0 + pp;
    int y = px / 160, x = px - y * 160;
    float logit = so[a][pp];
    float sc = 1.f / (1.f + expf(-logit));
    float ddx = so[9 + 4 * a][pp], ddy = so[10 + 4 * a][pp];
    float ddw = fminf(so[11 + 4 * a][pp], DWH);
    float ddh = fminf(so[12 + 4 * a][pp], DWH);
    float ax1 = x * 16.f + c_bx1[a];
    float ay1 = y * 16.f + c_by1[a];
    float ax2 = x * 16.f + c_bx2[a];
    float ay2 = y * 16.f + c_by2[a];
    float aw = ax2 - ax1, ah = ay2 - ay1;
    float cx = ax1 + 0.5f * aw, cy = ay1 + 0.5f * ah;
    float pcx = ddx * aw + cx, pcy = ddy * ah + cy;
    float pw = expf(ddw) * aw, phh = expf(ddh) * ah;
    float x1 = pcx - 0.5f * pw, y1 = pcy - 0.5f * phh;
    float x2 = pcx + 0.5f * pw, y2 = pcy + 0.5f * phh;
    x1 = fminf(fmaxf(x1, 0.f), IMS); x2 = fminf(fmaxf(x2, 0.f), IMS);
    y1 = fminf(fmaxf(y1, 0.f), IMS); y2 = fminf(fmaxf(y2, 0.f), IMS);
    int gidx = px * 9 + a;
    boxes[gidx] = make_float4(x1, y1, x2, y2);
    scores[gidx] = sc;
    u32 sb = __float_as_uint(sc);
    u32 mono = (sb & 0x80000000u) ? ~sb : (sb | 0x80000000u);
    keys[gidx] = ((u64)mono << 32) | (u64)(0xFFFFFFFFu - (u32)gidx);
  }
}

// ---------------- 4. radix select (u64 keys, exact k-th largest) ----------------
__global__ void init_k(SelState* st) { st->prefix = 0; st->r = K_SEL; st->cnt = 0; }

__global__ __launch_bounds__(256) void hist_k(const u64* __restrict__ keys,
                                              const SelState* __restrict__ st,
                                              u32* __restrict__ hist, int pass) {
  int idx = blockIdx.x * 256 + threadIdx.x;
  u64 k = keys[idx];
  int shift = 48 - 16 * pass;
  bool m;
  if (pass == 0) m = true;
  else m = ((k >> (shift + 16)) == st->prefix);
  if (m) atomicAdd(&hist[(u32)((k >> shift) & 0xFFFF)], 1u);
}

__global__ __launch_bounds__(256) void scan_k(const u32* __restrict__ hist, SelState* st) {
  __shared__ u32 psum[256];
  int t = threadIdx.x;
  u32 s = 0;
  for (int b = 0; b < 256; b++) s += hist[t * 256 + b];
  psum[t] = s;
  __syncthreads();
  if (t == 0) {
    u32 r = st->r, cum = 0;
    int seg = 255;
    for (; seg > 0; seg--) { if (cum + psum[seg] >= r) break; cum += psum[seg]; }
    int b = seg * 256 + 255;
    for (;; b--) { u32 h = hist[b]; if (cum + h >= r) break; cum += h; if (b == seg * 256) break; }
    st->prefix = (st->prefix << 16) | (u64)(u32)(b & 0xFFFF);
    st->r = r - cum;
  }
}

__global__ __launch_bounds__(256) void compact_k(const u64* __restrict__ keys,
                                                 SelState* st, u64* __restrict__ selk) {
  int idx = blockIdx.x * 256 + threadIdx.x;
  u64 k = keys[idx];
  if (k >= st->prefix) {
    u32 pos = atomicAdd(&st->cnt, 1u);
    selk[pos] = k;
  }
}

// ---------------- 5. exact rank (distinct keys) -> sorted SoA ----------------
__global__ __launch_bounds__(64) void rank_k(const u64* __restrict__ selk,
                                             const float4* __restrict__ boxes,
                                             const float* __restrict__ scores,
                                             float* sx1, float* sy1, float* sx2, float* sy2, float* ssc) {
  __shared__ __align__(16) u64 sk[SEL_PAD];
  int lane = threadIdx.x;
  for (int i = lane; i < SEL_PAD; i += 64) sk[i] = (i < K_SEL) ? selk[i] : 0ull;
  __syncthreads();
  int n = blockIdx.x * 64 + lane;
  u64 myk = (n < K_SEL) ? selk[n] : ~0ull;
  int cnt = 0;
  const ulonglong2* sk2 = (const ulonglong2*)sk;
  for (int j = 0; j < SEL_PAD / 2; j++) {
    ulonglong2 kk = sk2[j];
    cnt += (kk.x > myk) ? 1 : 0;
    cnt += (kk.y > myk) ? 1 : 0;
  }
  if (n < K_SEL) {
    u32 oidx = 0xFFFFFFFFu - (u32)(myk & 0xFFFFFFFFull);
    float4 b = boxes[oidx];
    sx1[cnt] = b.x; sy1[cnt] = b.y; sx2[cnt] = b.z; sy2[cnt] = b.w;
    ssc[cnt] = scores[oidx];
  }
}

// ---------------- 6. pairwise suppression mask (column-major only) ----------------
__global__ __launch_bounds__(256) void mask_k(const float* __restrict__ sx1, const float* __restrict__ sy1,
                                              const float* __restrict__ sx2, const float* __restrict__ sy2,
                                              u64* __restrict__ maskT) {
  __shared__ float jb[5][3008];
  int tid = threadIdx.x;
  int wv = tid >> 6, lane = tid & 63;
  int ibase = blockIdx.x * 32 + wv * 8;
  float ix1[8], iy1[8], ix2[8], iy2[8], ia[8];
#pragma unroll
  for (int r = 0; r < 8; r++) {
    int i = ibase + r;
    ix1[r] = sx1[i]; iy1[r] = sy1[i]; ix2[r] = sx2[i]; iy2[r] = sy2[i];
    ia[r] = (ix2[r] - ix1[r]) * (iy2[r] - iy1[r]);
  }
  for (int half = 0; half < 2; half++) {
    int j0 = half * 3008;
    __syncthreads();
    for (int idx = tid; idx < 3008; idx += 256) {
      int j = j0 + idx;
      bool v = j < K_SEL;
      float a = v ? sx1[j] : 0.f;
      float b = v ? sy1[j] : 0.f;
      float c = v ? sx2[j] : 0.f;
      float d = v ? sy2[j] : 0.f;
      jb[0][idx] = a; jb[1][idx] = b; jb[2][idx] = c; jb[3][idx] = d;
      jb[4][idx] = (c - a) * (d - b);
    }
    __syncthreads();
    for (int wi = 0; wi < 47; wi++) {
      int w = half * 47 + wi;
      int jl = wi * 64 + lane;
      int j = j0 + jl;
      float jx1 = jb[0][jl], jy1 = jb[1][jl], jx2 = jb[2][jl], jy2 = jb[3][jl], ja = jb[4][jl];
      bool jv = j < K_SEL;
#pragma unroll
      for (int r = 0; r < 8; r++) {
        int i = ibase + r;
        float xl = fmaxf(ix1[r], jx1), yt = fmaxf(iy1[r], jy1);
        float xr = fminf(ix2[r], jx2), yb = fminf(iy2[r], jy2);
        float iw = fmaxf(xr - xl, 0.f), ihh = fmaxf(yb - yt, 0.f);
        float inter = iw * ihh;
        bool sup = jv && (j > i) && (inter > 0.7f * (ia[r] + ja - inter));
        u64 bits = __ballot(sup);
        if (lane == 0 && i < K_SEL) maskT[(size_t)w * SEL_PAD + i] = bits;
      }
    }
  }
}

// ---------------- 7. greedy NMS: column-sweep pull (1 wave) ----------------
// For chunk c: supp[c] = OR of maskT[c][i] over previously-KEPT i (contiguous,
// coalesced ulonglong2 loads, kept-filter from LDS, lane OR-reduce). Then
// in-register greedy walk of the 64-box chunk using diag words + shfl64.
__global__ __launch_bounds__(64) void nms_k(const u64* __restrict__ maskT,
                                            const float* __restrict__ sx1, const float* __restrict__ sy1,
                                            const float* __restrict__ sx2, const float* __restrict__ sy2,
                                            u64* __restrict__ alive_out) {
  __shared__ u64 skept[94];
  __shared__ u64 svalid[94];
  int lane = threadIdx.x;
#pragma unroll 4
  for (int w = 0; w < 94; w++) {
    int p = w * 64 + lane;
    bool ok = false;
    if (p < K_SEL) {
      float bw = sx2[p] - sx1[p], bh = sy2[p] - sy1[p];
      ok = (bw >= 16.f) && (bh >= 16.f);
    }
    u64 bits = __ballot(ok);
    if (lane == 0) svalid[w] = bits;
  }
  __syncthreads();
  for (int c = 0; c < 94; c++) {
    size_t colbase = (size_t)c * SEL_PAD;
    u64 d = maskT[colbase + c * 64 + lane];      // diag: row (c*64+lane), word c
    u64 acc = 0;
    int nb = c >> 1;
    for (int b = 0; b < nb; b++) {
      ulonglong2 v = *(const ulonglong2*)&maskT[colbase + b * 128 + 2 * lane];
      u64 kw = skept[2 * b + (lane >> 5)];
      int sh = (2 * lane) & 63;
      if ((kw >> sh) & 1) acc |= v.x;
      if ((kw >> (sh + 1)) & 1) acc |= v.y;
    }
    if (c & 1) {
      u64 v = maskT[colbase + (size_t)nb * 128 + lane];
      u64 kw = skept[c - 1];
      if ((kw >> lane) & 1) acc |= v;
    }
    u32 lo = (u32)acc, hi = (u32)(acc >> 32);
#pragma unroll
    for (int off = 1; off < 64; off <<= 1) {
      lo |= (u32)__shfl_xor((int)lo, off, 64);
      hi |= (u32)__shfl_xor((int)hi, off, 64);
    }
    u64 supp = ((u64)hi << 32) | (u64)lo;
    u64 cur = svalid[c] & ~supp;
    u64 kept = 0, rem = cur;
    while (rem) {
      int b = __builtin_ctzll(rem);
      kept |= (1ull << b);
      u64 dead = shfl64(d, b);                   // row b's word c: what b suppresses here
      rem &= ~dead;
      rem &= ~(1ull << b);
    }
    if (lane == 0) skept[c] = kept;
    __syncthreads();
  }
  alive_out[lane] = skept[lane];
  if (lane < 30) alive_out[64 + lane] = skept[64 + lane];
}

// ---------------- 8. finalize: first 300 kept (then suppressed, score -1) ----------------
__global__ __launch_bounds__(128) void final_k(const u64* __restrict__ alive,
                                               const float* __restrict__ sx1, const float* __restrict__ sy1,
                                               const float* __restrict__ sx2, const float* __restrict__ sy2,
                                               const float* __restrict__ ssc, float* __restrict__ out) {
  __shared__ u64 aw[94];
  __shared__ u32 pre[95];
  int tid = threadIdx.x;
  if (tid < 94) aw[tid] = alive[tid];
  __syncthreads();
  if (tid == 0) {
    u32 s = 0;
    for (int w = 0; w < 94; w++) { pre[w] = s; s += (u32)__popcll(aw[w]); }
    pre[94] = s;
  }
  __syncthreads();
  u32 total = pre[94];
  for (int p = tid; p < K_SEL; p += 128) {
    int w = p >> 6, b = p & 63;
    u64 word = aw[w];
    u32 kb = pre[w] + (u32)__popcll(word & ((1ull << b) - 1ull));
    bool kept = (word >> b) & 1ull;
    int slot = -1; float sc = -1.f;
    if (kept) {
      if (kb < 300) { slot = (int)kb; sc = ssc[p]; }
    } else {
      u32 s2 = total + (u32)p - kb;
      if (s2 < 300) slot = (int)s2;
    }
    if (slot >= 0) {
      out[slot * 5 + 0] = sx1[p];
      out[slot * 5 + 1] = sy1[p];
      out[slot * 5 + 2] = sx2[p];
      out[slot * 5 + 3] = sy2[p];
      out[slot * 5 + 4] = sc;
    }
  }
}

extern "C" void kernel_launch(void* const* d_in, const int* in_sizes, int n_in,
                              void* d_out, int out_size, void* d_ws, size_t ws_size,
                              hipStream_t stream) {
  const float* feat   = (const float*)d_in[0];
  const float* conv_w = (const float*)d_in[2];
  const float* conv_b = (const float*)d_in[3];
  const float* cls_w  = (const float*)d_in[4];
  const float* cls_b  = (const float*)d_in[5];
  const float* bbox_w = (const float*)d_in[6];
  const float* bbox_b = (const float*)d_in[7];
  float* out = (float*)d_out;
  char* ws = (char*)d_ws;

  float*  pf     = (float*)(ws + OFF_PF);
  float*  rpn    = (float*)(ws + OFF_RPN);
  float4* boxes  = (float4*)(ws + OFF_BOXES);
  float*  scores = (float*)(ws + OFF_SCORES);
  u64*    keys   = (u64*)(ws + OFF_KEYS);
  u32*    hist   = (u32*)(ws + OFF_HIST);
  SelState* st   = (SelState*)(ws + OFF_STATE);
  u64*    selk   = (u64*)(ws + OFF_SELK);
  float*  sx1    = (float*)(ws + OFF_SX1);
  float*  sy1    = (float*)(ws + OFF_SY1);
  float*  sx2    = (float*)(ws + OFF_SX2);
  float*  sy2    = (float*)(ws + OFF_SY2);
  float*  ssc    = (float*)(ws + OFF_SSC);
  u64*    alive  = (u64*)(ws + OFF_ALIVE);
  u64*    maskT  = (u64*)(ws + OFF_MASKT);

  pad_k<<<27216, 256, 0, stream>>>(feat, pf);
  conv_k<<<800, 256, 0, stream>>>(pf, conv_w, conv_b, rpn);
  heads_k<<<800, 256, 0, stream>>>(rpn, cls_w, cls_b, bbox_w, bbox_b, boxes, scores, keys);

  init_k<<<1, 1, 0, stream>>>(st);
  for (int pass = 0; pass < 4; pass++) {
    hipMemsetAsync(hist, 0, 65536 * sizeof(u32), stream);
    hist_k<<<900, 256, 0, stream>>>(keys, st, hist, pass);
    scan_k<<<1, 256, 0, stream>>>(hist, st);
  }
  compact_k<<<900, 256, 0, stream>>>(keys, st, selk);
  rank_k<<<94, 64, 0, stream>>>(selk, boxes, scores, sx1, sy1, sx2, sy2, ssc);
  mask_k<<<188, 256, 0, stream>>>(sx1, sy1, sx2, sy2, maskT);
  nms_k<<<1, 64, 0, stream>>>(maskT, sx1, sy1, sx2, sy2, alive);
  final_k<<<1, 128, 0, stream>>>(alive, sx1, sy1, sx2, sy2, ssc, out);
}

// Round 4
// 2125.024 us; speedup vs baseline: 1.2369x; 1.2369x over previous
//
#include <hip/hip_runtime.h>
#include <math.h>

typedef unsigned long long u64;
typedef unsigned int u32;

#define HH 160
#define WW 160
#define CC 256
#define NPX 25600
#define NA 9
#define NSC 230400
#define K_SEL 6000
#define SEL_PAD 6016
#define IMS 2560.0f
#define DWH 4.135166556742356f

struct SelState { u64 prefix; u32 r; u32 cnt; };

// ---- ws layout (bytes) ----
#define OFF_BOXES   0u               // float4[230400] -> 3,686,400
#define OFF_SCORES  3686400u         // float [230400]
#define OFF_KEYS    4608000u         // u64   [230400]
#define OFF_HIST    6451200u         // u32   [65536]
#define OFF_STATE   6713344u
#define OFF_SELK    6713600u         // u64[6016]
#define OFF_SX1     6761728u
#define OFF_SY1     6785792u
#define OFF_SX2     6809856u
#define OFF_SY2     6833920u
#define OFF_SSC     6857984u
#define OFF_ALIVE   6882048u
#define OFF_MASKT   11503104u        // u64[94*6016 + 128 pad] -> ends 16,028,160
#define OFF_RPN     27869184u        // float[256*160*160] -> ends 54,083,584

__constant__ float c_bx1[9] = {-91.f,-181.f,-362.f,-64.f,-128.f,-256.f,-45.f,-91.f,-181.f};
__constant__ float c_by1[9] = {-45.f,-91.f,-181.f,-64.f,-128.f,-256.f,-91.f,-181.f,-362.f};
__constant__ float c_bx2[9] = { 91.f, 181.f, 362.f, 64.f, 128.f, 256.f, 45.f, 91.f, 181.f};
__constant__ float c_by2[9] = { 45.f,  91.f, 181.f, 64.f, 128.f, 256.f, 91.f, 181.f, 362.f};

__device__ inline u64 shfl64(u64 v, int src) {
  int lo = (int)(v & 0xFFFFFFFFull), hi = (int)(v >> 32);
  lo = __shfl(lo, src, 64); hi = __shfl(hi, src, 64);
  return ((u64)(u32)hi << 32) | (u32)lo;
}

// ---------------- 1. conv3x3 + bias + relu, padding fused (implicit GEMM, fp32) ----------------
__global__ __launch_bounds__(256) void conv_k(const float* __restrict__ feat,
                                              const float* __restrict__ w,
                                              const float* __restrict__ bias,
                                              float* __restrict__ outp) {
  int bx = blockIdx.x;            // 800 = 5 * 40 * 4
  int ct = bx % 5;
  int rt = (bx / 5) % 40;
  int ot = bx / 200;
  int x0 = ct * 32, y0 = rt * 4, oc0 = ot * 64;

  __shared__ float wsm[72][68];   // [k = icl*9+tap][oc]
  __shared__ float ps[8][6][36];  // [icl][row][col]

  int tid = threadIdx.x;
  int og = tid >> 5;
  int pg = tid & 31;
  int row = pg >> 3;
  int col = (pg & 7) * 4;

  float acc[8][4];
#pragma unroll
  for (int i = 0; i < 8; i++)
#pragma unroll
    for (int j = 0; j < 4; j++) acc[i][j] = 0.f;

  for (int ic0 = 0; ic0 < CC; ic0 += 8) {
    __syncthreads();
    for (int idx = tid; idx < 4608; idx += 256) {
      int oc = idx / 72, j = idx % 72;
      wsm[j][oc] = w[(oc0 + oc) * 2304 + ic0 * 9 + j];
    }
    for (int idx = tid; idx < 1632; idx += 256) {
      int icl = idx / 204, rem = idx % 204;
      int r = rem / 34, cc2 = rem % 34;
      int gy = y0 + r - 1, gx = x0 + cc2 - 1;
      float v = 0.f;
      if ((unsigned)gy < 160u && (unsigned)gx < 160u)
        v = feat[(ic0 + icl) * NPX + gy * WW + gx];
      ps[icl][r][cc2] = v;
    }
    __syncthreads();
#pragma unroll
    for (int icl = 0; icl < 8; icl++) {
#pragma unroll
      for (int dy = 0; dy < 3; dy++) {
        float4 b03 = *(const float4*)&ps[icl][row + dy][col];
        float2 b45 = *(const float2*)&ps[icl][row + dy][col + 4];
        float bb[6] = {b03.x, b03.y, b03.z, b03.w, b45.x, b45.y};
#pragma unroll
        for (int dxx = 0; dxx < 3; dxx++) {
          int k = icl * 9 + dy * 3 + dxx;
          float4 a03 = *(const float4*)&wsm[k][og * 8];
          float4 a47 = *(const float4*)&wsm[k][og * 8 + 4];
          float av[8] = {a03.x, a03.y, a03.z, a03.w, a47.x, a47.y, a47.z, a47.w};
#pragma unroll
          for (int i = 0; i < 8; i++)
#pragma unroll
            for (int j = 0; j < 4; j++)
              acc[i][j] += av[i] * bb[dxx + j];
        }
      }
    }
  }
#pragma unroll
  for (int i = 0; i < 8; i++) {
    int oc = oc0 + og * 8 + i;
    float bv = bias[oc];
    float4 v;
    v.x = fmaxf(acc[i][0] + bv, 0.f);
    v.y = fmaxf(acc[i][1] + bv, 0.f);
    v.z = fmaxf(acc[i][2] + bv, 0.f);
    v.w = fmaxf(acc[i][3] + bv, 0.f);
    *(float4*)&outp[(size_t)oc * NPX + (y0 + row) * WW + x0 + col] = v;
  }
}

// ---------------- 2. heads + sigmoid + decode + clip + key ----------------
__global__ __launch_bounds__(256) void heads_k(const float* __restrict__ rpn,
                                               const float* __restrict__ cls_w,
                                               const float* __restrict__ cls_b,
                                               const float* __restrict__ bbox_w,
                                               const float* __restrict__ bbox_b,
                                               float4* __restrict__ boxes,
                                               float* __restrict__ scores,
                                               u64* __restrict__ keys) {
  __shared__ float sf[32][260];
  __shared__ float so[45][33];
  int tid = threadIdx.x;
  int px0 = blockIdx.x * 32;
  for (int idx = tid; idx < 8192; idx += 256) {
    int c = idx >> 5, p = idx & 31;
    sf[p][c] = rpn[(size_t)c * NPX + px0 + p];
  }
  __syncthreads();
  int p = tid & 31, g = tid >> 5;
  for (int oi = 0; oi < 6; oi++) {
    int o = g + oi * 8;
    if (o >= 45) break;
    const float* wr = (o < 9) ? (cls_w + o * CC) : (bbox_w + (o - 9) * CC);
    float bsum = (o < 9) ? cls_b[o] : bbox_b[o - 9];
    float s = 0.f;
    for (int c = 0; c < CC; c += 4) {
      float4 f = *(const float4*)&sf[p][c];
      float4 wv = *(const float4*)&wr[c];
      s += f.x * wv.x; s += f.y * wv.y; s += f.z * wv.z; s += f.w * wv.w;
    }
    so[o][p] = s + bsum;
  }
  __syncthreads();
  for (int t = tid; t < 288; t += 256) {
    int a = t >> 5, pp = t & 31;
    int px = px0 + pp;
    int y = px / 160, x = px - y * 160;
    float logit = so[a][pp];
    float sc = 1.f / (1.f + expf(-logit));
    float ddx = so[9 + 4 * a][pp], ddy = so[10 + 4 * a][pp];
    float ddw = fminf(so[11 + 4 * a][pp], DWH);
    float ddh = fminf(so[12 + 4 * a][pp], DWH);
    float ax1 = x * 16.f + c_bx1[a];
    float ay1 = y * 16.f + c_by1[a];
    float ax2 = x * 16.f + c_bx2[a];
    float ay2 = y * 16.f + c_by2[a];
    float aw = ax2 - ax1, ah = ay2 - ay1;
    float cx = ax1 + 0.5f * aw, cy = ay1 + 0.5f * ah;
    float pcx = ddx * aw + cx, pcy = ddy * ah + cy;
    float pw = expf(ddw) * aw, phh = expf(ddh) * ah;
    float x1 = pcx - 0.5f * pw, y1 = pcy - 0.5f * phh;
    float x2 = pcx + 0.5f * pw, y2 = pcy + 0.5f * phh;
    x1 = fminf(fmaxf(x1, 0.f), IMS); x2 = fminf(fmaxf(x2, 0.f), IMS);
    y1 = fminf(fmaxf(y1, 0.f), IMS); y2 = fminf(fmaxf(y2, 0.f), IMS);
    int gidx = px * 9 + a;
    boxes[gidx] = make_float4(x1, y1, x2, y2);
    scores[gidx] = sc;
    u32 sb = __float_as_uint(sc);
    u32 mono = (sb & 0x80000000u) ? ~sb : (sb | 0x80000000u);
    keys[gidx] = ((u64)mono << 32) | (u64)(0xFFFFFFFFu - (u32)gidx);
  }
}

// ---------------- 3. radix select ----------------
__global__ __launch_bounds__(256) void hist_k(const u64* __restrict__ keys,
                                              const SelState* __restrict__ st,
                                              u32* __restrict__ hist, int pass) {
  int idx = blockIdx.x * 256 + threadIdx.x;
  u64 k = keys[idx];
  int shift = 48 - 16 * pass;
  bool m;
  if (pass == 0) m = true;
  else m = ((k >> (shift + 16)) == st->prefix);
  if (m) atomicAdd(&hist[(u32)((k >> shift) & 0xFFFF)], 1u);
}

// scan + self-zero (for next pass) + cnt reset on last pass
__global__ __launch_bounds__(256) void scan_k(u32* __restrict__ hist, SelState* st, int pass) {
  __shared__ u32 psum[256];
  int t = threadIdx.x;
  u32 s = 0;
  for (int b = 0; b < 256; b++) s += hist[t * 256 + b];
  psum[t] = s;
  __syncthreads();
  if (t == 0) {
    u32 r = (pass == 0) ? (u32)K_SEL : st->r;
    u64 pre = (pass == 0) ? 0ull : st->prefix;
    u32 cum = 0;
    int seg = 255;
    for (; seg > 0; seg--) { if (cum + psum[seg] >= r) break; cum += psum[seg]; }
    int b = seg * 256 + 255;
    for (;; b--) { u32 h = hist[b]; if (cum + h >= r) break; cum += h; if (b == seg * 256) break; }
    st->prefix = (pre << 16) | (u64)(u32)(b & 0xFFFF);
    st->r = r - cum;
    if (pass == 3) st->cnt = 0;
  }
  __syncthreads();
  for (int b = 0; b < 256; b++) hist[t * 256 + b] = 0;
}

__global__ __launch_bounds__(256) void compact_k(const u64* __restrict__ keys,
                                                 SelState* st, u64* __restrict__ selk) {
  int idx = blockIdx.x * 256 + threadIdx.x;
  u64 k = keys[idx];
  if (k >= st->prefix) {
    u32 pos = atomicAdd(&st->cnt, 1u);
    selk[pos] = k;
  }
}

// ---------------- 4. exact rank -> sorted SoA ----------------
__global__ __launch_bounds__(64) void rank_k(const u64* __restrict__ selk,
                                             const float4* __restrict__ boxes,
                                             const float* __restrict__ scores,
                                             float* sx1, float* sy1, float* sx2, float* sy2, float* ssc) {
  __shared__ __align__(16) u64 sk[SEL_PAD];
  int lane = threadIdx.x;
  for (int i = lane; i < SEL_PAD; i += 64) sk[i] = (i < K_SEL) ? selk[i] : 0ull;
  __syncthreads();
  int n = blockIdx.x * 64 + lane;
  u64 myk = (n < K_SEL) ? selk[n] : ~0ull;
  int cnt = 0;
  const ulonglong2* sk2 = (const ulonglong2*)sk;
  for (int j = 0; j < SEL_PAD / 2; j++) {
    ulonglong2 kk = sk2[j];
    cnt += (kk.x > myk) ? 1 : 0;
    cnt += (kk.y > myk) ? 1 : 0;
  }
  if (n < K_SEL) {
    u32 oidx = 0xFFFFFFFFu - (u32)(myk & 0xFFFFFFFFull);
    float4 b = boxes[oidx];
    sx1[cnt] = b.x; sy1[cnt] = b.y; sx2[cnt] = b.z; sy2[cnt] = b.w;
    ssc[cnt] = scores[oidx];
  }
}

// ---------------- 5. pairwise suppression mask (column-major) ----------------
__global__ __launch_bounds__(256) void mask_k(const float* __restrict__ sx1, const float* __restrict__ sy1,
                                              const float* __restrict__ sx2, const float* __restrict__ sy2,
                                              u64* __restrict__ maskT) {
  __shared__ float jb[5][3008];
  int tid = threadIdx.x;
  int wv = tid >> 6, lane = tid & 63;
  int ibase = blockIdx.x * 32 + wv * 8;
  float ix1[8], iy1[8], ix2[8], iy2[8], ia[8];
#pragma unroll
  for (int r = 0; r < 8; r++) {
    int i = ibase + r;
    ix1[r] = sx1[i]; iy1[r] = sy1[i]; ix2[r] = sx2[i]; iy2[r] = sy2[i];
    ia[r] = (ix2[r] - ix1[r]) * (iy2[r] - iy1[r]);
  }
  for (int half = 0; half < 2; half++) {
    int j0 = half * 3008;
    __syncthreads();
    for (int idx = tid; idx < 3008; idx += 256) {
      int j = j0 + idx;
      bool v = j < K_SEL;
      float a = v ? sx1[j] : 0.f;
      float b = v ? sy1[j] : 0.f;
      float c = v ? sx2[j] : 0.f;
      float d = v ? sy2[j] : 0.f;
      jb[0][idx] = a; jb[1][idx] = b; jb[2][idx] = c; jb[3][idx] = d;
      jb[4][idx] = (c - a) * (d - b);
    }
    __syncthreads();
    for (int wi = 0; wi < 47; wi++) {
      int w = half * 47 + wi;
      int jl = wi * 64 + lane;
      int j = j0 + jl;
      float jx1 = jb[0][jl], jy1 = jb[1][jl], jx2 = jb[2][jl], jy2 = jb[3][jl], ja = jb[4][jl];
      bool jv = j < K_SEL;
#pragma unroll
      for (int r = 0; r < 8; r++) {
        int i = ibase + r;
        float xl = fmaxf(ix1[r], jx1), yt = fmaxf(iy1[r], jy1);
        float xr = fminf(ix2[r], jx2), yb = fminf(iy2[r], jy2);
        float iw = fmaxf(xr - xl, 0.f), ihh = fmaxf(yb - yt, 0.f);
        float inter = iw * ihh;
        bool sup = jv && (j > i) && (inter > 0.7f * (ia[r] + ja - inter));
        u64 bits = __ballot(sup);
        if (lane == 0 && i < K_SEL) maskT[(size_t)w * SEL_PAD + i] = bits;
      }
    }
  }
}

// ---------------- 6. greedy NMS: multi-wave column pull (1 block x 16 waves) ----------------
// skept[96] pre-zeroed in LDS => unwritten (future) chunks filter to zero, so
// phase A issues 3 unconditional independent 16B loads per thread (no gating).
__global__ __launch_bounds__(1024) void nms_k(const u64* __restrict__ maskT,
                                              const float* __restrict__ sx1, const float* __restrict__ sy1,
                                              const float* __restrict__ sx2, const float* __restrict__ sy2,
                                              u64* __restrict__ alive_out) {
  __shared__ u64 sdiag[94 * 64];   // 48128 B
  __shared__ u64 skept[96];
  __shared__ u64 svalid[94];
  __shared__ u64 wacc[16];
  int tid = threadIdx.x;
  int wv = tid >> 6, lane = tid & 63;

  if (tid < 96) skept[tid] = 0ull;
  // min-size validity bitmap
  for (int w = wv; w < 94; w += 16) {
    int p = w * 64 + lane;
    float bw = sx2[p] - sx1[p], bh = sy2[p] - sy1[p];
    bool ok = (p < K_SEL) && (bw >= 16.f) && (bh >= 16.f);
    u64 bits = __ballot(ok);
    if (lane == 0) svalid[w] = bits;
  }
  // preload all diagonal 64x64 blocks
  for (int idx = tid; idx < 94 * 64; idx += 1024) {
    int cc = idx >> 6;
    sdiag[idx] = maskT[(size_t)cc * SEL_PAD + cc * 64 + (idx & 63)];
  }
  __syncthreads();

  for (int c = 0; c < 94; c++) {
    size_t colbase = (size_t)c * SEL_PAD;
    int i0 = 2 * tid;
    // 3 independent loads cover i in [0, 6144) (allocation padded; filter kills junk)
    ulonglong2 v0 = *(const ulonglong2*)&maskT[colbase + i0];
    ulonglong2 v1 = *(const ulonglong2*)&maskT[colbase + i0 + 2048];
    ulonglong2 v2 = *(const ulonglong2*)&maskT[colbase + i0 + 4096];
    u64 k0 = skept[i0 >> 6];
    u64 k1 = skept[(i0 + 2048) >> 6];
    u64 k2 = skept[(i0 + 4096) >> 6];
    int sh = i0 & 63;
    u64 acc = 0;
    if ((k0 >> sh) & 1) acc |= v0.x;
    if ((k0 >> (sh + 1)) & 1) acc |= v0.y;
    if ((k1 >> sh) & 1) acc |= v1.x;
    if ((k1 >> (sh + 1)) & 1) acc |= v1.y;
    if ((k2 >> sh) & 1) acc |= v2.x;
    if ((k2 >> (sh + 1)) & 1) acc |= v2.y;
    // wave OR-reduce
    u32 lo = (u32)acc, hi = (u32)(acc >> 32);
#pragma unroll
    for (int off = 1; off < 64; off <<= 1) {
      lo |= (u32)__shfl_xor((int)lo, off, 64);
      hi |= (u32)__shfl_xor((int)hi, off, 64);
    }
    if (lane == 0) wacc[wv] = ((u64)hi << 32) | (u64)lo;
    __syncthreads();
    if (wv == 0) {
      u64 a = wacc[lane & 15];
      u32 alo = (u32)a, ahi = (u32)(a >> 32);
#pragma unroll
      for (int off = 1; off < 16; off <<= 1) {
        alo |= (u32)__shfl_xor((int)alo, off, 64);
        ahi |= (u32)__shfl_xor((int)ahi, off, 64);
      }
      u64 supp = ((u64)ahi << 32) | (u64)alo;
      u64 cur = svalid[c] & ~supp;
      u64 d = sdiag[c * 64 + lane];
      u64 rem = cur, kept = 0;
      while (rem) {
        int b = __builtin_ctzll(rem);
        kept |= (1ull << b);
        u64 dead = shfl64(d, b);
        rem &= ~dead;
        rem &= ~(1ull << b);
      }
      if (lane == 0) skept[c] = kept;
    }
    __syncthreads();
  }
  if (tid < 94) alive_out[tid] = skept[tid];
}

// ---------------- 7. finalize: first 300 kept (then suppressed, score -1) ----------------
__global__ __launch_bounds__(128) void final_k(const u64* __restrict__ alive,
                                               const float* __restrict__ sx1, const float* __restrict__ sy1,
                                               const float* __restrict__ sx2, const float* __restrict__ sy2,
                                               const float* __restrict__ ssc, float* __restrict__ out) {
  __shared__ u64 aw[94];
  __shared__ u32 pre[95];
  int tid = threadIdx.x;
  if (tid < 94) aw[tid] = alive[tid];
  __syncthreads();
  if (tid == 0) {
    u32 s = 0;
    for (int w = 0; w < 94; w++) { pre[w] = s; s += (u32)__popcll(aw[w]); }
    pre[94] = s;
  }
  __syncthreads();
  u32 total = pre[94];
  for (int p = tid; p < K_SEL; p += 128) {
    int w = p >> 6, b = p & 63;
    u64 word = aw[w];
    u32 kb = pre[w] + (u32)__popcll(word & ((1ull << b) - 1ull));
    bool kept = (word >> b) & 1ull;
    int slot = -1; float sc = -1.f;
    if (kept) {
      if (kb < 300) { slot = (int)kb; sc = ssc[p]; }
    } else {
      u32 s2 = total + (u32)p - kb;
      if (s2 < 300) slot = (int)s2;
    }
    if (slot >= 0) {
      out[slot * 5 + 0] = sx1[p];
      out[slot * 5 + 1] = sy1[p];
      out[slot * 5 + 2] = sx2[p];
      out[slot * 5 + 3] = sy2[p];
      out[slot * 5 + 4] = sc;
    }
  }
}

extern "C" void kernel_launch(void* const* d_in, const int* in_sizes, int n_in,
                              void* d_out, int out_size, void* d_ws, size_t ws_size,
                              hipStream_t stream) {
  const float* feat   = (const float*)d_in[0];
  const float* conv_w = (const float*)d_in[2];
  const float* conv_b = (const float*)d_in[3];
  const float* cls_w  = (const float*)d_in[4];
  const float* cls_b  = (const float*)d_in[5];
  const float* bbox_w = (const float*)d_in[6];
  const float* bbox_b = (const float*)d_in[7];
  float* out = (float*)d_out;
  char* ws = (char*)d_ws;

  float*  rpn    = (float*)(ws + OFF_RPN);
  float4* boxes  = (float4*)(ws + OFF_BOXES);
  float*  scores = (float*)(ws + OFF_SCORES);
  u64*    keys   = (u64*)(ws + OFF_KEYS);
  u32*    hist   = (u32*)(ws + OFF_HIST);
  SelState* st   = (SelState*)(ws + OFF_STATE);
  u64*    selk   = (u64*)(ws + OFF_SELK);
  float*  sx1    = (float*)(ws + OFF_SX1);
  float*  sy1    = (float*)(ws + OFF_SY1);
  float*  sx2    = (float*)(ws + OFF_SX2);
  float*  sy2    = (float*)(ws + OFF_SY2);
  float*  ssc    = (float*)(ws + OFF_SSC);
  u64*    alive  = (u64*)(ws + OFF_ALIVE);
  u64*    maskT  = (u64*)(ws + OFF_MASKT);

  hipMemsetAsync(hist, 0, 65536 * sizeof(u32), stream);
  conv_k<<<800, 256, 0, stream>>>(feat, conv_w, conv_b, rpn);
  heads_k<<<800, 256, 0, stream>>>(rpn, cls_w, cls_b, bbox_w, bbox_b, boxes, scores, keys);

  for (int pass = 0; pass < 4; pass++) {
    hist_k<<<900, 256, 0, stream>>>(keys, st, hist, pass);
    scan_k<<<1, 256, 0, stream>>>(hist, st, pass);
  }
  compact_k<<<900, 256, 0, stream>>>(keys, st, selk);
  rank_k<<<94, 64, 0, stream>>>(selk, boxes, scores, sx1, sy1, sx2, sy2, ssc);
  mask_k<<<188, 256, 0, stream>>>(sx1, sy1, sx2, sy2, maskT);
  nms_k<<<1, 1024, 0, stream>>>(maskT, sx1, sy1, sx2, sy2, alive);
  final_k<<<1, 128, 0, stream>>>(alive, sx1, sy1, sx2, sy2, ssc, out);
}